// Round 15
// baseline (248.865 us; speedup 1.0000x reference)
//
#include <hip/hip_runtime.h>

#define SS 1024
#define BB 4096
#define HH 8
#define XSTRIDE (BB * HH)   // floats per timestep slice

// DPP cross-lane (VALU pipe). quad_perm xor1/2/3; row_half_mirror (s^7);
// row_ror:8 (s^8 within each 16-lane row).
__device__ __forceinline__ int dpp_x1(int v) { return __builtin_amdgcn_mov_dpp(v, 0xB1, 0xF, 0xF, true); }
__device__ __forceinline__ int dpp_x2(int v) { return __builtin_amdgcn_mov_dpp(v, 0x4E, 0xF, 0xF, true); }
__device__ __forceinline__ int dpp_x3(int v) { return __builtin_amdgcn_mov_dpp(v, 0x1B, 0xF, 0xF, true); }
__device__ __forceinline__ int dpp_x7(int v) { return __builtin_amdgcn_mov_dpp(v, 0x141, 0xF, 0xF, true); }
__device__ __forceinline__ int dpp_r8(int v) { return __builtin_amdgcn_mov_dpp(v, 0x128, 0xF, 0xF, true); }

// xor16 within each 32-lane group (BitMode: xor=0x10, and=0x1F -> 0x401F).
__device__ __forceinline__ float swz16(float v) {
    return __int_as_float(__builtin_amdgcn_ds_swizzle(__float_as_int(v), 0x401F));
}
// pair-combine with partner lane s^8 (same 16-row): VALU DPP.
__device__ __forceinline__ float comb8(float p) {
    return p + __int_as_float(dpp_r8(__float_as_int(p)));
}

// Pinned distributed load: 4B/lane (element e0 of this lane's batch).
#define ALOADD(DST, PTR) asm volatile("global_load_dword %0, %1, off" : "=v"(DST) : "v"(PTR))

#define WAITV(N) do {                                                                  \
    asm volatile("s_waitcnt vmcnt(" #N ")" ::: "memory");                              \
    __builtin_amdgcn_sched_barrier(0);                                                 \
} while (0)

// Full X pre-activation for step V. Lane covers 2 columns {e0, e0^1} of its
// row; 4 t-lanes cover all 8. Reduce: r8 pair-add, then xor16 ds_swizzle.
// Commutative grouping -> all 4 replicas bit-identical.
#define XFULL(BUF, V) do {                                                             \
    const float va = BUF[V];                                                           \
    const float vb = __int_as_float(dpp_x1(__float_as_int(va)));                       \
    float sr = fmaf(va, wri0, bias_rx); sr = fmaf(vb, wri1, sr);                       \
    float sz = fmaf(va, wzi0, bias_zx); sz = fmaf(vb, wzi1, sz);                       \
    float sn = fmaf(va, wni0, bias_nx); sn = fmaf(vb, wni1, sn);                       \
    const float srp = comb8(sr), szp = comb8(sz), snp = comb8(sn);                     \
    xr[V] = srp + swz16(srp);                                                          \
    xz[V] = szp + swz16(szp);                                                          \
    xn[V] = snp + swz16(snp);                                                          \
} while (0)

// One 8-step group: R-steps with X(u+2) woven (3 slices) into the
// transcendental stall windows (r13's proven schedule, 32-lane math).
#define GROUP(BUF, SBASE) do {                                                         \
    XFULL(BUF, 0);                                                                     \
    XFULL(BUF, 1);                                                                     \
    _Pragma("unroll")                                                                  \
    for (int u = 0; u < 8; ++u) {                                                      \
        /* h-dots: 6 FMA over this lane's 2 columns */                                 \
        const float hb = __int_as_float(dpp_x1(__float_as_int(hv)));                   \
        float pr = hv * wrh0;               pr = fmaf(hb, wrh1, pr);                   \
        float pz = hv * wzh0;               pz = fmaf(hb, wzh1, pz);                   \
        float pn = fmaf(hv, wnh0, bias_nh); pn = fmaf(hb, wnh1, pn);                   \
        const float prp = comb8(pr), pzp = comb8(pz), pnp = comb8(pn);                 \
        const float srr = xr[u] + (prp + swz16(prp));                                  \
        const float szz = xz[u] + (pzp + swz16(pzp));                                  \
        const float snn = pnp + swz16(pnp);                                            \
        const bool W = (u + 2 < 8);                                                    \
        float wsr, wsz, wsn, wsrp, wszp, wsnp;                                         \
        if (W) {   /* X(u+2) slice 1: dpp + 6 FMA */                                   \
            const float va2 = BUF[u + 2];                                              \
            const float vb2 = __int_as_float(dpp_x1(__float_as_int(va2)));             \
            wsr = fmaf(va2, wri0, bias_rx); wsr = fmaf(vb2, wri1, wsr);                \
            wsz = fmaf(va2, wzi0, bias_zx); wsz = fmaf(vb2, wzi1, wsz);                \
            wsn = fmaf(va2, wni0, bias_nx); wsn = fmaf(vb2, wni1, wsn);                \
        }                                                                              \
        const float er = __builtin_amdgcn_exp2f(srr);                                  \
        const float ez = __builtin_amdgcn_exp2f(szz);                                  \
        if (W) {   /* X(u+2) slice 2: r8 pair-combines */                              \
            wsrp = comb8(wsr); wszp = comb8(wsz); wsnp = comb8(wsn);                   \
        }                                                                              \
        const float r_ = __builtin_amdgcn_rcpf(1.0f + er);                             \
        const float z_ = __builtin_amdgcn_rcpf(1.0f + ez);                             \
        if (W) {   /* X(u+2) slice 3: xor16 + stage */                                 \
            xr[u + 2] = wsrp + swz16(wsrp);                                            \
            xz[u + 2] = wszp + swz16(wszp);                                            \
            xn[u + 2] = wsnp + swz16(wsnp);                                            \
        }                                                                              \
        const float en = __builtin_amdgcn_exp2f(fmaf(r_, snn, xn[u]));                 \
        const float n_ = fmaf(-2.0f, __builtin_amdgcn_rcpf(1.0f + en), 1.0f);          \
        h = n_ + z_ * (h - n_);                                                        \
        /* rebuild replica h[e0], e0 = j ^ 2t: candidates xor{0,2,4,6}, select by t */ \
        const int hbits = __float_as_int(h);                                           \
        const int t7 = dpp_x7(hbits);                                                  \
        const float cb = __int_as_float(dpp_x2(hbits));   /* xor2 */                   \
        const float cc = __int_as_float(dpp_x3(t7));      /* xor4 */                   \
        const float cd = __int_as_float(dpp_x1(t7));      /* xor6 */                   \
        hv = tHi ? (tOdd ? cd : cc) : (tOdd ? cb : h);                                 \
        /* dup-store: all 4 t-lanes hold identical h[j]; coalescer merges */           \
        __builtin_nontemporal_store(h, &op[(size_t)((SBASE) + u) * XSTRIDE]);          \
    }                                                                                  \
} while (0)

// 8 pinned dword loads = one 8-step group (1 per step per lane).
#define LOADG(BUF, GRP) do {                                                           \
    const float* bp_ = xq + (size_t)(GRP) * 8 * XSTRIDE;                               \
    _Pragma("unroll")                                                                  \
    for (int u_ = 0; u_ < 8; ++u_) ALOADD(BUF[u_], bp_ + (size_t)u_ * XSTRIDE);        \
} while (0)

// 32 lanes per batch element (row j = s&7, column-pair t = s>>3), 2 batches
// per wave, 2048 waves = 2 waves/SIMD: hardware TLP fills the recurrence
// chain's stall windows with the co-resident wave's ready instructions.
__global__ __launch_bounds__(64, 2) void gru_kernel(
    const float* __restrict__ x,
    const float* __restrict__ w_ih,
    const float* __restrict__ w_hh,
    const float* __restrict__ b_ih,
    const float* __restrict__ b_hh,
    float* __restrict__ out)
{
    const int lane = threadIdx.x;
    const int s32 = lane & 31;
    const int j = s32 & 7;
    const int t = s32 >> 3;            // 0..3
    const int e0 = j ^ (t << 1);       // replica element this lane holds
    const bool tOdd = (t & 1) != 0;
    const bool tHi  = (t & 2) != 0;

    const float SR = -1.4426950408889634f; // -log2(e): sigmoid scale
    const float SN = 2.8853900817779268f;  // 2*log2(e): tanh scale

    // Weights for row j, columns {e0, e0^1} (pre-scaled).
    const float wri0 = SR * w_ih[j * 8 + e0],        wri1 = SR * w_ih[j * 8 + (e0 ^ 1)];
    const float wzi0 = SR * w_ih[(8 + j) * 8 + e0],  wzi1 = SR * w_ih[(8 + j) * 8 + (e0 ^ 1)];
    const float wni0 = SN * w_ih[(16 + j) * 8 + e0], wni1 = SN * w_ih[(16 + j) * 8 + (e0 ^ 1)];
    const float wrh0 = SR * w_hh[j * 8 + e0],        wrh1 = SR * w_hh[j * 8 + (e0 ^ 1)];
    const float wzh0 = SR * w_hh[(8 + j) * 8 + e0],  wzh1 = SR * w_hh[(8 + j) * 8 + (e0 ^ 1)];
    const float wnh0 = SN * w_hh[(16 + j) * 8 + e0], wnh1 = SN * w_hh[(16 + j) * 8 + (e0 ^ 1)];

    // Biases only in the t==0 partials (added exactly once by the reduce).
    const bool t0lane = (t == 0);
    const float bias_rx = t0lane ? SR * (b_ih[j] + b_hh[j]) : 0.0f;
    const float bias_zx = t0lane ? SR * (b_ih[8 + j] + b_hh[8 + j]) : 0.0f;
    const float bias_nx = t0lane ? SN * b_ih[16 + j] : 0.0f;
    const float bias_nh = t0lane ? SN * b_hh[16 + j] : 0.0f;

    // Addresses: batch bg = blockIdx*2 + (lane>>5). Loads fetch element e0;
    // stores write row j (dup x4 across t-lanes, same value -> merged).
    const int bslice = (blockIdx.x << 4) + ((lane >> 5) << 3);
    const float* xq = x + bslice + e0;
    float* op = out + bslice + j;
    float* hlast = out + (size_t)SS * BB * HH + bslice + j;

    float xA[8], xB[8];   // distributed x: 1 dword/lane/step

    // prologue: groups 0 -> A, 1 -> B; retire A's 8 (B's 8 stay in flight)
    LOADG(xA, 0);
    LOADG(xB, 1);
    WAITV(8);

    float h = 0.0f;
    float hv = 0.0f;      // replica h[e0]
    float xr[8], xz[8], xn[8];

    // r13's proven schedule: steady state at each WAITV(16): newest 16 =
    // this group's 8 stores + just-issued 8 loads; older loads retired.
    for (int g = 0; g < 124; g += 2) {
        GROUP(xA, g * 8);
        LOADG(xA, g + 2);
        WAITV(16);
        GROUP(xB, (g + 1) * 8);
        LOADG(xB, g + 3);
        WAITV(16);
    }
    GROUP(xA, 992);  LOADG(xA, 126); WAITV(16);
    GROUP(xB, 1000); LOADG(xB, 127); WAITV(16);
    GROUP(xA, 1008); WAITV(8);
    GROUP(xB, 1016);

    *hlast = h;
}

extern "C" void kernel_launch(void* const* d_in, const int* in_sizes, int n_in,
                              void* d_out, int out_size, void* d_ws, size_t ws_size,
                              hipStream_t stream) {
    const float* x    = (const float*)d_in[0];
    const float* w_ih = (const float*)d_in[1];
    const float* w_hh = (const float*)d_in[2];
    const float* b_ih = (const float*)d_in[3];
    const float* b_hh = (const float*)d_in[4];
    float* out = (float*)d_out;
    gru_kernel<<<BB / 2, 64, 0, stream>>>(x, w_ih, w_hh, b_ih, b_hh, out);
}